// Round 1
// baseline (698.975 us; speedup 1.0000x reference)
//
#include <hip/hip_runtime.h>
#include <math.h>

#define NN 4096
#define DD 512
#define NC 10
#define NG 2

#define BM 128
#define BN 128
#define BK 32
#define LDA (BM + 4)   // padded leading dim (floats); keeps 16B alignment per k-row

// ---------------------------------------------------------------------------
// Kernel 1: per-row squared norms for teacher (nt) and student (ns).
// One wave per row; 2048 blocks x 256 threads cover 8192 rows.
// ---------------------------------------------------------------------------
__global__ void k_rownorms(const float* __restrict__ ft, const float* __restrict__ fs,
                           float* __restrict__ nt, float* __restrict__ ns) {
    int wid  = threadIdx.x >> 6;
    int lane = threadIdx.x & 63;
    int r = blockIdx.x * 4 + wid;          // 0..8191
    const float* src;
    float* dst;
    int row;
    if (r < NN) { src = ft; dst = nt; row = r; }
    else        { src = fs; dst = ns; row = r - NN; }
    const float4* p = (const float4*)(src + (size_t)row * DD);
    float s = 0.0f;
#pragma unroll
    for (int c = 0; c < (DD / 4) / 64; ++c) {   // 2 float4 per lane
        float4 v = p[lane + 64 * c];
        s += v.x * v.x + v.y * v.y + v.z * v.z + v.w * v.w;
    }
#pragma unroll
    for (int o = 32; o; o >>= 1) s += __shfl_xor(s, o);
    if (lane == 0) dst[row] = s;
}

// ---------------------------------------------------------------------------
// Kernel 2: column sums of teacher and student (for closed-form sigma).
// 256 blocks: b&1 selects matrix, b>>1 selects a 32-row chunk.
// ---------------------------------------------------------------------------
__global__ void k_colsums(const float* __restrict__ ft, const float* __restrict__ fs,
                          float* __restrict__ sumT, float* __restrict__ sumS) {
    int b = blockIdx.x;
    int mat = b & 1;
    int chunk = b >> 1;                     // 0..127
    const float* src = mat ? fs : ft;
    float* dst = mat ? sumS : sumT;
    int r0 = chunk * 32;
    int c0 = threadIdx.x, c1 = threadIdx.x + 256;
    float a0 = 0.0f, a1 = 0.0f;
    for (int r = r0; r < r0 + 32; ++r) {
        a0 += src[(size_t)r * DD + c0];
        a1 += src[(size_t)r * DD + c1];
    }
    atomicAdd(&dst[c0], a0);
    atomicAdd(&dst[c1], a1);
}

// ---------------------------------------------------------------------------
// Kernel 3: sigma_avg (closed form) -> inv_scale = 1/(2*sigma_avg)
// mean(D_TS) = sum(nt)/N + sum(ns)/N - 2*(sumT . sumS)/N^2
// ---------------------------------------------------------------------------
__global__ void k_scale(const float* __restrict__ nt, const float* __restrict__ ns,
                        const float* __restrict__ sumT, const float* __restrict__ sumS,
                        float* __restrict__ invscale) {
    __shared__ float red[8];
    int tid = threadIdx.x;
    float s = 0.0f;
    for (int i = tid; i < NN; i += 256) s += nt[i] + ns[i];
    float d = 0.0f;
    for (int i = tid; i < DD; i += 256) d += sumT[i] * sumS[i];
#pragma unroll
    for (int o = 32; o; o >>= 1) { s += __shfl_xor(s, o); d += __shfl_xor(d, o); }
    int wid = tid >> 6, lane = tid & 63;
    if (lane == 0) { red[wid] = s; red[wid + 4] = d; }
    __syncthreads();
    if (tid == 0) {
        float S  = red[0] + red[1] + red[2] + red[3];
        float Dt = red[4] + red[5] + red[6] + red[7];
        float sigma = S / (float)NN - 2.0f * Dt / ((float)NN * (float)NN);
        invscale[0] = 1.0f / (2.0f * sigma);   // SIGMA_BASE = 1
    }
}

// ---------------------------------------------------------------------------
// Kernel 4: fused Gram + exp + masked per-row sums.
// MODE 0 = TT (pred: label match, 1 accumulator)
// MODE 1 = SS (pred: label && group match, 1 accumulator)
// MODE 2 = TS (pred: label match, 2 accumulators keyed by student group)
// 128x128 tile / block(256), 8x8 microtile, BK=32.
// ---------------------------------------------------------------------------
template <int MODE>
__global__ __launch_bounds__(256) void k_gram(
    const float* __restrict__ Arow, const float* __restrict__ Bcol,
    const float* __restrict__ nA, const float* __restrict__ nB,
    const int* __restrict__ labA, const int* __restrict__ labB,
    const int* __restrict__ grpA, const int* __restrict__ grpB,
    const float* __restrict__ invscale_p,
    float* __restrict__ z0, float* __restrict__ z1) {

    __shared__ float As[BK][LDA];
    __shared__ float Bs[BK][LDA];
    __shared__ float nBs[BN];
    __shared__ int   labBs[BN];
    __shared__ int   grpBs[BN];

    int tid = threadIdx.x;
    int i0 = blockIdx.y * BM;
    int j0 = blockIdx.x * BN;
    float inv_scale = invscale_p[0];

    if (tid < BN) {
        nBs[tid]   = nB[j0 + tid];
        labBs[tid] = labB[j0 + tid];
        grpBs[tid] = (MODE == 0) ? 0 : grpB[j0 + tid];
    }

    int tm = tid >> 4;    // 0..15  row group
    int tn = tid & 15;    // 0..15  col group (low lane bits)

    float acc[8][8] = {};

    const float4* A4 = (const float4*)Arow;
    const float4* B4 = (const float4*)Bcol;

    for (int k0 = 0; k0 < DD; k0 += BK) {
        __syncthreads();
#pragma unroll
        for (int l = 0; l < 4; ++l) {
            int e  = tid + l * 256;     // 0..1023 float4 slots
            int m  = e >> 3;            // row in tile
            int kq = e & 7;             // float4 index within the 32-wide k chunk
            float4 va = A4[(size_t)(i0 + m) * (DD / 4) + (k0 >> 2) + kq];
            As[kq * 4 + 0][m] = va.x; As[kq * 4 + 1][m] = va.y;
            As[kq * 4 + 2][m] = va.z; As[kq * 4 + 3][m] = va.w;
            float4 vb = B4[(size_t)(j0 + m) * (DD / 4) + (k0 >> 2) + kq];
            Bs[kq * 4 + 0][m] = vb.x; Bs[kq * 4 + 1][m] = vb.y;
            Bs[kq * 4 + 2][m] = vb.z; Bs[kq * 4 + 3][m] = vb.w;
        }
        __syncthreads();
#pragma unroll
        for (int kk = 0; kk < BK; ++kk) {
            float a[8], b[8];
            *(float4*)&a[0] = *(const float4*)&As[kk][tm * 8];
            *(float4*)&a[4] = *(const float4*)&As[kk][tm * 8 + 4];
            *(float4*)&b[0] = *(const float4*)&Bs[kk][tn * 8];
            *(float4*)&b[4] = *(const float4*)&Bs[kk][tn * 8 + 4];
#pragma unroll
            for (int im = 0; im < 8; ++im)
#pragma unroll
                for (int in = 0; in < 8; ++in)
                    acc[im][in] = fmaf(a[im], b[in], acc[im][in]);
        }
    }

    // epilogue: D = nA + nB - 2*dot, clamp, exp, predicate, per-row sums
    int ibase = i0 + tm * 8;
    float rs0[8] = {};
    float rs1[8] = {};
#pragma unroll
    for (int im = 0; im < 8; ++im) {
        int i = ibase + im;
        float ni = nA[i];
        int li = labA[i];
        int gi = (MODE == 1) ? grpA[i] : 0;
#pragma unroll
        for (int in = 0; in < 8; ++in) {
            int jn = tn * 8 + in;
            float d = ni + nBs[jn] - 2.0f * acc[im][in];
            d = fmaxf(d, 1e-12f);
            float kv = __expf(-d * inv_scale);
            bool ok = (li == labBs[jn]);
            if (MODE == 1) ok = ok && (gi == grpBs[jn]);
            if (MODE == 2) {
                rs0[im] += (ok && grpBs[jn] == 0) ? kv : 0.0f;
                rs1[im] += (ok && grpBs[jn] == 1) ? kv : 0.0f;
            } else {
                rs0[im] += ok ? kv : 0.0f;
            }
        }
    }
    // reduce across the 16 tn lanes (low 4 lane bits)
#pragma unroll
    for (int im = 0; im < 8; ++im) {
#pragma unroll
        for (int o = 1; o < 16; o <<= 1) {
            rs0[im] += __shfl_xor(rs0[im], o);
            if (MODE == 2) rs1[im] += __shfl_xor(rs1[im], o);
        }
    }
    if (tn == 0) {
#pragma unroll
        for (int im = 0; im < 8; ++im) {
            atomicAdd(&z0[ibase + im], rs0[im]);
            if (MODE == 2) atomicAdd(&z1[ibase + im], rs1[im]);
        }
    }
}

// ---------------------------------------------------------------------------
// Kernel 5: bucket the per-row sums, compute final scalar.
// ---------------------------------------------------------------------------
__global__ void k_final(const int* __restrict__ labels, const int* __restrict__ groups,
                        const float* __restrict__ zTT, const float* __restrict__ zSS,
                        const float* __restrict__ zTS, float* __restrict__ out) {
    __shared__ float cnt_t[NC], cnt_s[NC * NG];
    __shared__ float nTT[NC], nSS[NC * NG], nTS[NC * NG];
    int tid = threadIdx.x;
    if (tid < NC) { cnt_t[tid] = 0.0f; nTT[tid] = 0.0f; }
    if (tid < NC * NG) { cnt_s[tid] = 0.0f; nSS[tid] = 0.0f; nTS[tid] = 0.0f; }
    __syncthreads();
    for (int i = tid; i < NN; i += 256) {
        int l = labels[i], g = groups[i];
        atomicAdd(&cnt_t[l], 1.0f);
        atomicAdd(&cnt_s[l * NG + g], 1.0f);
        atomicAdd(&nTT[l], zTT[i]);
        atomicAdd(&nSS[l * NG + g], zSS[i]);
        atomicAdd(&nTS[l * NG + 0], zTS[i]);
        atomicAdd(&nTS[l * NG + 1], zTS[NN + i]);
    }
    __syncthreads();
    if (tid == 0) {
        float total = 0.0f;
        for (int c = 0; c < NC; ++c) {
            float ntc = cnt_t[c];
            float sn = fmaxf(ntc, 1.0f);
            float meanTT = nTT[c] / (sn * sn);
            for (int g = 0; g < NG; ++g) {
                float nsg = cnt_s[c * NG + g];
                float ss = fmaxf(nsg, 1.0f);
                float meanSS = nSS[c * NG + g] / (ss * ss);
                float meanTS = nTS[c * NG + g] / (sn * ss);
                if (ntc > 0.0f && nsg > 0.0f)
                    total += meanTT + meanSS - 2.0f * meanTS;
            }
        }
        out[0] = 0.5f * total;   // W_M = 1
    }
}

// ---------------------------------------------------------------------------
// workspace layout (floats):
// 0      nt[4096]
// 4096   ns[4096]
// 8192   sumT[512]      <- zero region start
// 8704   sumS[512]
// 9216   zTT[4096]
// 13312  zSS[4096]
// 17408  zTS[2*4096]
// 25600  invscale[1]    <- zero region end (exclusive)
// ---------------------------------------------------------------------------
extern "C" void kernel_launch(void* const* d_in, const int* in_sizes, int n_in,
                              void* d_out, int out_size, void* d_ws, size_t ws_size,
                              hipStream_t stream) {
    const float* fs     = (const float*)d_in[0];
    const float* ft     = (const float*)d_in[1];
    const int*   groups = (const int*)d_in[2];
    const int*   labels = (const int*)d_in[3];

    float* ws   = (float*)d_ws;
    float* nt   = ws;
    float* ns   = ws + 4096;
    float* sumT = ws + 8192;
    float* sumS = ws + 8704;
    float* zTT  = ws + 9216;
    float* zSS  = ws + 13312;
    float* zTS  = ws + 17408;
    float* invs = ws + 25600;

    hipMemsetAsync(ws + 8192, 0, (size_t)17408 * sizeof(float), stream);

    k_rownorms<<<2048, 256, 0, stream>>>(ft, fs, nt, ns);
    k_colsums<<<256, 256, 0, stream>>>(ft, fs, sumT, sumS);
    k_scale<<<1, 256, 0, stream>>>(nt, ns, sumT, sumS, invs);

    dim3 grid(NN / BN, NN / BM);
    // TT: teacher x teacher, label predicate
    k_gram<0><<<grid, 256, 0, stream>>>(ft, ft, nt, nt, labels, labels,
                                        nullptr, nullptr, invs, zTT, nullptr);
    // SS: student x student, label+group predicate
    k_gram<1><<<grid, 256, 0, stream>>>(fs, fs, ns, ns, labels, labels,
                                        groups, groups, invs, zSS, nullptr);
    // TS: teacher rows x student cols, label predicate, split by student group
    k_gram<2><<<grid, 256, 0, stream>>>(ft, fs, nt, ns, labels, labels,
                                        nullptr, groups, invs, zTS, zTS + NN);

    k_final<<<1, 256, 0, stream>>>(labels, groups, zTT, zSS, zTS, (float*)d_out);
}

// Round 2
// 249.595 us; speedup vs baseline: 2.8004x; 2.8004x over previous
//
#include <hip/hip_runtime.h>
#include <math.h>

#define NN 4096
#define DD 512
#define NC 10
#define NG 2

#define BM 128
#define BN 128
#define BK 32

typedef __bf16 bf16x8 __attribute__((ext_vector_type(8)));
typedef float f32x4 __attribute__((ext_vector_type(4)));

__device__ __forceinline__ void load_lds16(const __bf16* g, __bf16* l) {
    __builtin_amdgcn_global_load_lds((const __attribute__((address_space(1))) void*)g,
                                     (__attribute__((address_space(3))) void*)l, 16, 0, 0);
}

// ---------------------------------------------------------------------------
// Kernel 0: fp32 -> bf16 conversion (RNE). 2048 blocks: b<1024 teacher, else student.
// Each thread converts 8 floats -> one 16B bf16x8 store.
// ---------------------------------------------------------------------------
__global__ void k_cvt(const float* __restrict__ ft, const float* __restrict__ fs,
                      __bf16* __restrict__ at, __bf16* __restrict__ as_) {
    int b = blockIdx.x;
    const float* src = (b < 1024) ? ft : fs;
    __bf16* dst = (b < 1024) ? at : as_;
    int idx = ((b & 1023) * 256 + threadIdx.x) * 8;
    float4 v0 = *(const float4*)(src + idx);
    float4 v1 = *(const float4*)(src + idx + 4);
    bf16x8 r;
    r[0] = (__bf16)v0.x; r[1] = (__bf16)v0.y; r[2] = (__bf16)v0.z; r[3] = (__bf16)v0.w;
    r[4] = (__bf16)v1.x; r[5] = (__bf16)v1.y; r[6] = (__bf16)v1.z; r[7] = (__bf16)v1.w;
    *(bf16x8*)(dst + idx) = r;
}

// ---------------------------------------------------------------------------
// Kernel 1: per-row squared norms (fp32, exact).
// ---------------------------------------------------------------------------
__global__ void k_rownorms(const float* __restrict__ ft, const float* __restrict__ fs,
                           float* __restrict__ nt, float* __restrict__ ns) {
    int wid  = threadIdx.x >> 6;
    int lane = threadIdx.x & 63;
    int r = blockIdx.x * 4 + wid;
    const float* src;
    float* dst;
    int row;
    if (r < NN) { src = ft; dst = nt; row = r; }
    else        { src = fs; dst = ns; row = r - NN; }
    const float4* p = (const float4*)(src + (size_t)row * DD);
    float s = 0.0f;
#pragma unroll
    for (int c = 0; c < (DD / 4) / 64; ++c) {
        float4 v = p[lane + 64 * c];
        s += v.x * v.x + v.y * v.y + v.z * v.z + v.w * v.w;
    }
#pragma unroll
    for (int o = 32; o; o >>= 1) s += __shfl_xor(s, o);
    if (lane == 0) dst[row] = s;
}

// ---------------------------------------------------------------------------
// Kernel 2: column sums (for closed-form sigma).
// ---------------------------------------------------------------------------
__global__ void k_colsums(const float* __restrict__ ft, const float* __restrict__ fs,
                          float* __restrict__ sumT, float* __restrict__ sumS) {
    int b = blockIdx.x;
    int mat = b & 1;
    int chunk = b >> 1;
    const float* src = mat ? fs : ft;
    float* dst = mat ? sumS : sumT;
    int r0 = chunk * 32;
    int c0 = threadIdx.x, c1 = threadIdx.x + 256;
    float a0 = 0.0f, a1 = 0.0f;
    for (int r = r0; r < r0 + 32; ++r) {
        a0 += src[(size_t)r * DD + c0];
        a1 += src[(size_t)r * DD + c1];
    }
    atomicAdd(&dst[c0], a0);
    atomicAdd(&dst[c1], a1);
}

// ---------------------------------------------------------------------------
// Kernel 3: inv_scale = 1/(2*sigma_avg), sigma closed form.
// ---------------------------------------------------------------------------
__global__ void k_scale(const float* __restrict__ nt, const float* __restrict__ ns,
                        const float* __restrict__ sumT, const float* __restrict__ sumS,
                        float* __restrict__ invscale) {
    __shared__ float red[8];
    int tid = threadIdx.x;
    float s = 0.0f;
    for (int i = tid; i < NN; i += 256) s += nt[i] + ns[i];
    float d = 0.0f;
    for (int i = tid; i < DD; i += 256) d += sumT[i] * sumS[i];
#pragma unroll
    for (int o = 32; o; o >>= 1) { s += __shfl_xor(s, o); d += __shfl_xor(d, o); }
    int wid = tid >> 6, lane = tid & 63;
    if (lane == 0) { red[wid] = s; red[wid + 4] = d; }
    __syncthreads();
    if (tid == 0) {
        float S  = red[0] + red[1] + red[2] + red[3];
        float Dt = red[4] + red[5] + red[6] + red[7];
        float sigma = S / (float)NN - 2.0f * Dt / ((float)NN * (float)NN);
        invscale[0] = 1.0f / (2.0f * sigma);
    }
}

// ---------------------------------------------------------------------------
// Kernel 4: MFMA Gram + exp + masked per-row sums.
// MODE 0 = TT (label match), MODE 1 = SS (label&&group), MODE 2 = TS (split by grpB)
// 128x128 tile, 4 waves, each wave 64x64 via 4x4 mfma_f32_16x16x32_bf16.
// LDS layout [kchunk=4][row=128][8] bf16 -> conflict-free ds_read_b128 fragments,
// written linearly by global_load_lds (permutation carried by per-lane global addr).
// ---------------------------------------------------------------------------
template <int MODE>
__global__ __launch_bounds__(256) void k_gram_mfma(
    const __bf16* __restrict__ A, const __bf16* __restrict__ B,
    const float* __restrict__ nA, const float* __restrict__ nB,
    const int* __restrict__ labA, const int* __restrict__ labB,
    const int* __restrict__ grpA, const int* __restrict__ grpB,
    const float* __restrict__ invscale_p,
    float* __restrict__ z0, float* __restrict__ z1) {

    __shared__ __bf16 As[4 * 128 * 8];
    __shared__ __bf16 Bs[4 * 128 * 8];

    int tid = threadIdx.x;
    int i0 = blockIdx.y * BM;
    int j0 = blockIdx.x * BN;

    int lane = tid & 63, wid = tid >> 6;
    int wr = wid >> 1, wc = wid & 1;
    int l15 = lane & 15, l4 = lane >> 4;

    // staging: thread t fills 16B LDS slots t and t+256; slot s=(q,r): q=s>>7, r=s&127
    int sr = tid & 127;
    int q0 = tid >> 7;       // 0..1
    const __bf16* gA0 = A + (size_t)(i0 + sr) * DD + q0 * 8;
    const __bf16* gA1 = gA0 + 16;                 // q0+2 chunk
    const __bf16* gB0 = B + (size_t)(j0 + sr) * DD + q0 * 8;
    const __bf16* gB1 = gB0 + 16;
    __bf16* lA0 = &As[(size_t)tid * 8];
    __bf16* lA1 = &As[(size_t)(tid + 256) * 8];
    __bf16* lB0 = &Bs[(size_t)tid * 8];
    __bf16* lB1 = &Bs[(size_t)(tid + 256) * 8];

    f32x4 acc[4][4] = {};

    for (int k0 = 0; k0 < DD; k0 += BK) {
        load_lds16(gA0 + k0, lA0);
        load_lds16(gA1 + k0, lA1);
        load_lds16(gB0 + k0, lB0);
        load_lds16(gB1 + k0, lB1);
        __syncthreads();                 // drains vmcnt, LDS tile ready

        bf16x8 af[4], bf[4];
#pragma unroll
        for (int im = 0; im < 4; ++im)
            af[im] = *(const bf16x8*)&As[((size_t)l4 * 128 + wr * 64 + im * 16 + l15) * 8];
#pragma unroll
        for (int in = 0; in < 4; ++in)
            bf[in] = *(const bf16x8*)&Bs[((size_t)l4 * 128 + wc * 64 + in * 16 + l15) * 8];
#pragma unroll
        for (int im = 0; im < 4; ++im)
#pragma unroll
            for (int in = 0; in < 4; ++in)
                acc[im][in] = __builtin_amdgcn_mfma_f32_16x16x32_bf16(af[im], bf[in], acc[im][in], 0, 0, 0);
        __syncthreads();                 // all reads done before next staging
    }

    // epilogue
    float inv_scale = invscale_p[0];
    int ibase = i0 + wr * 64;
    int jbase = j0 + wc * 64;
    float nBv[4];
    int labBv[4], grpBv[4];
#pragma unroll
    for (int in = 0; in < 4; ++in) {
        int j = jbase + in * 16 + l15;
        nBv[in] = nB[j];
        labBv[in] = labB[j];
        grpBv[in] = (MODE == 0) ? 0 : grpB[j];
    }
#pragma unroll
    for (int im = 0; im < 4; ++im) {
#pragma unroll
        for (int j = 0; j < 4; ++j) {
            int row = ibase + im * 16 + l4 * 4 + j;
            float ni = nA[row];
            int li = labA[row];
            int gi = (MODE == 1) ? grpA[row] : 0;
            float s0 = 0.0f, s1 = 0.0f;
#pragma unroll
            for (int in = 0; in < 4; ++in) {
                float d = ni + nBv[in] - 2.0f * acc[im][in][j];
                d = fmaxf(d, 1e-12f);
                float kv = __expf(-d * inv_scale);
                bool ok = (li == labBv[in]);
                if (MODE == 1) ok = ok && (gi == grpBv[in]);
                if (MODE == 2) {
                    s0 += (ok && grpBv[in] == 0) ? kv : 0.0f;
                    s1 += (ok && grpBv[in] == 1) ? kv : 0.0f;
                } else {
                    s0 += ok ? kv : 0.0f;
                }
            }
#pragma unroll
            for (int o = 1; o < 16; o <<= 1) {
                s0 += __shfl_xor(s0, o);
                if (MODE == 2) s1 += __shfl_xor(s1, o);
            }
            if (l15 == 0) {
                atomicAdd(&z0[row], s0);
                if (MODE == 2) atomicAdd(&z1[row], s1);
            }
        }
    }
}

// ---------------------------------------------------------------------------
// Kernel 5: bucket per-row sums, final scalar.
// ---------------------------------------------------------------------------
__global__ void k_final(const int* __restrict__ labels, const int* __restrict__ groups,
                        const float* __restrict__ zTT, const float* __restrict__ zSS,
                        const float* __restrict__ zTS, float* __restrict__ out) {
    __shared__ float cnt_t[NC], cnt_s[NC * NG];
    __shared__ float nTT[NC], nSS[NC * NG], nTS[NC * NG];
    int tid = threadIdx.x;
    if (tid < NC) { cnt_t[tid] = 0.0f; nTT[tid] = 0.0f; }
    if (tid < NC * NG) { cnt_s[tid] = 0.0f; nSS[tid] = 0.0f; nTS[tid] = 0.0f; }
    __syncthreads();
    for (int i = tid; i < NN; i += 256) {
        int l = labels[i], g = groups[i];
        atomicAdd(&cnt_t[l], 1.0f);
        atomicAdd(&cnt_s[l * NG + g], 1.0f);
        atomicAdd(&nTT[l], zTT[i]);
        atomicAdd(&nSS[l * NG + g], zSS[i]);
        atomicAdd(&nTS[l * NG + 0], zTS[i]);
        atomicAdd(&nTS[l * NG + 1], zTS[NN + i]);
    }
    __syncthreads();
    if (tid == 0) {
        float total = 0.0f;
        for (int c = 0; c < NC; ++c) {
            float ntc = cnt_t[c];
            float sn = fmaxf(ntc, 1.0f);
            float meanTT = nTT[c] / (sn * sn);
            for (int g = 0; g < NG; ++g) {
                float nsg = cnt_s[c * NG + g];
                float ss = fmaxf(nsg, 1.0f);
                float meanSS = nSS[c * NG + g] / (ss * ss);
                float meanTS = nTS[c * NG + g] / (sn * ss);
                if (ntc > 0.0f && nsg > 0.0f)
                    total += meanTT + meanSS - 2.0f * meanTS;
            }
        }
        out[0] = 0.5f * total;
    }
}

// ---------------------------------------------------------------------------
// workspace layout:
// bytes [0, 4MB)      : teacher bf16 [4096][512]
// bytes [4MB, 8MB)    : student bf16 [4096][512]
// floats from 8MB:
//   +0      nt[4096]
//   +4096   ns[4096]
//   +8192   sumT[512]      <- zero region start
//   +8704   sumS[512]
//   +9216   zTT[4096]
//   +13312  zSS[4096]
//   +17408  zTS[2*4096]
//   +25600  invscale[1]    <- zero region end
// ---------------------------------------------------------------------------
extern "C" void kernel_launch(void* const* d_in, const int* in_sizes, int n_in,
                              void* d_out, int out_size, void* d_ws, size_t ws_size,
                              hipStream_t stream) {
    const float* fs     = (const float*)d_in[0];
    const float* ft     = (const float*)d_in[1];
    const int*   groups = (const int*)d_in[2];
    const int*   labels = (const int*)d_in[3];

    __bf16* Abf = (__bf16*)d_ws;                       // teacher
    __bf16* Bbf = (__bf16*)d_ws + (size_t)NN * DD;     // student
    float* wsf  = (float*)((char*)d_ws + (size_t)2 * NN * DD * sizeof(__bf16));
    float* nt   = wsf;
    float* ns   = wsf + 4096;
    float* sumT = wsf + 8192;
    float* sumS = wsf + 8704;
    float* zTT  = wsf + 9216;
    float* zSS  = wsf + 13312;
    float* zTS  = wsf + 17408;
    float* invs = wsf + 25600;

    hipMemsetAsync(wsf + 8192, 0, (size_t)17408 * sizeof(float), stream);

    k_cvt<<<2048, 256, 0, stream>>>(ft, fs, Abf, Bbf);
    k_rownorms<<<2048, 256, 0, stream>>>(ft, fs, nt, ns);
    k_colsums<<<256, 256, 0, stream>>>(ft, fs, sumT, sumS);
    k_scale<<<1, 256, 0, stream>>>(nt, ns, sumT, sumS, invs);

    dim3 grid(NN / BN, NN / BM);
    k_gram_mfma<0><<<grid, 256, 0, stream>>>(Abf, Abf, nt, nt, labels, labels,
                                             nullptr, nullptr, invs, zTT, nullptr);
    k_gram_mfma<1><<<grid, 256, 0, stream>>>(Bbf, Bbf, ns, ns, labels, labels,
                                             groups, groups, invs, zSS, nullptr);
    k_gram_mfma<2><<<grid, 256, 0, stream>>>(Abf, Bbf, nt, ns, labels, labels,
                                             nullptr, groups, invs, zTS, zTS + NN);

    k_final<<<1, 256, 0, stream>>>(labels, groups, zTT, zSS, zTS, (float*)d_out);
}

// Round 3
// 247.904 us; speedup vs baseline: 2.8195x; 1.0068x over previous
//
#include <hip/hip_runtime.h>
#include <math.h>

#define NN 4096
#define DD 512
#define NC 10
#define NG 2

#define BM 128
#define BN 128
#define BK 64
#define NT (DD / BK)   // 8 K-steps

typedef __bf16 bf16x8 __attribute__((ext_vector_type(8)));
typedef __bf16 bf16x4 __attribute__((ext_vector_type(4)));
typedef float f32x4 __attribute__((ext_vector_type(4)));

__device__ __forceinline__ void load_lds16(const __bf16* g, __bf16* l) {
    __builtin_amdgcn_global_load_lds((const __attribute__((address_space(1))) void*)g,
                                     (__attribute__((address_space(3))) void*)l, 16, 0, 0);
}

// ---------------------------------------------------------------------------
// Kernel 1: fused fp32->bf16 convert + per-row squared norms (fp32 exact).
// 2048 blocks x 256; one wave per row (8192 rows across both matrices).
// ---------------------------------------------------------------------------
__global__ void k_prep(const float* __restrict__ ft, const float* __restrict__ fs,
                       __bf16* __restrict__ at, __bf16* __restrict__ as_,
                       float* __restrict__ nt, float* __restrict__ ns) {
    int wid  = threadIdx.x >> 6;
    int lane = threadIdx.x & 63;
    int r = blockIdx.x * 4 + wid;
    const float* src; __bf16* bdst; float* ndst; int row;
    if (r < NN) { src = ft; bdst = at;  ndst = nt; row = r; }
    else        { src = fs; bdst = as_; ndst = ns; row = r - NN; }
    const float4* p = (const float4*)(src + (size_t)row * DD);
    float s = 0.0f;
#pragma unroll
    for (int c = 0; c < 2; ++c) {
        float4 v = p[lane + 64 * c];
        s += v.x * v.x + v.y * v.y + v.z * v.z + v.w * v.w;
        bf16x4 b;
        b[0] = (__bf16)v.x; b[1] = (__bf16)v.y; b[2] = (__bf16)v.z; b[3] = (__bf16)v.w;
        *(bf16x4*)(bdst + (size_t)row * DD + (lane + 64 * c) * 4) = b;
    }
#pragma unroll
    for (int o = 32; o; o >>= 1) s += __shfl_xor(s, o);
    if (lane == 0) ndst[row] = s;
}

// ---------------------------------------------------------------------------
// Kernel 2: column sums (fp32 inputs, for closed-form sigma).
// ---------------------------------------------------------------------------
__global__ void k_colsums(const float* __restrict__ ft, const float* __restrict__ fs,
                          float* __restrict__ sumT, float* __restrict__ sumS) {
    int b = blockIdx.x;
    int mat = b & 1;
    int chunk = b >> 1;
    const float* src = mat ? fs : ft;
    float* dst = mat ? sumS : sumT;
    int r0 = chunk * 32;
    int c0 = threadIdx.x, c1 = threadIdx.x + 256;
    float a0 = 0.0f, a1 = 0.0f;
    for (int r = r0; r < r0 + 32; ++r) {
        a0 += src[(size_t)r * DD + c0];
        a1 += src[(size_t)r * DD + c1];
    }
    atomicAdd(&dst[c0], a0);
    atomicAdd(&dst[c1], a1);
}

// ---------------------------------------------------------------------------
// Kernel 3: inv_scale = 1/(2*sigma_avg), sigma closed form:
// mean(D_TS) = (sum nt + sum ns)/N - 2*(sumT . sumS)/N^2
// ---------------------------------------------------------------------------
__global__ void k_scale(const float* __restrict__ nt, const float* __restrict__ ns,
                        const float* __restrict__ sumT, const float* __restrict__ sumS,
                        float* __restrict__ invscale) {
    __shared__ float red[8];
    int tid = threadIdx.x;
    float s = 0.0f;
    for (int i = tid; i < NN; i += 256) s += nt[i] + ns[i];
    float d = 0.0f;
    for (int i = tid; i < DD; i += 256) d += sumT[i] * sumS[i];
#pragma unroll
    for (int o = 32; o; o >>= 1) { s += __shfl_xor(s, o); d += __shfl_xor(d, o); }
    int wid = tid >> 6, lane = tid & 63;
    if (lane == 0) { red[wid] = s; red[wid + 4] = d; }
    __syncthreads();
    if (tid == 0) {
        float S  = red[0] + red[1] + red[2] + red[3];
        float Dt = red[4] + red[5] + red[6] + red[7];
        float sigma = S / (float)NN - 2.0f * Dt / ((float)NN * (float)NN);
        invscale[0] = 1.0f / (2.0f * sigma);
    }
}

// ---------------------------------------------------------------------------
// Kernel 4: all three Grams in one launch (blockIdx.z = mode).
// mode 0 = TT (label match), 1 = SS (label&&group), 2 = TS (split by grpB).
// 128x128 tile, 4 waves, 4x4 mfma_f32_16x16x32_bf16 per wave, BK=64,
// double-buffered LDS with stage-ahead (T3 minimal 2-phase):
//   iter t: STAGE(buf[t+1]) ; ds_read+MFMA on buf[t] ; __syncthreads (drain).
// LDS layout per buffer: [q=k/8][row=128][8] bf16 -> conflict-free ds_read_b128.
// ---------------------------------------------------------------------------
__global__ __launch_bounds__(256) void k_gram_all(
    const __bf16* __restrict__ T, const __bf16* __restrict__ S,
    const float* __restrict__ nt, const float* __restrict__ ns,
    const int* __restrict__ labels, const int* __restrict__ groups,
    const float* __restrict__ invscale_p,
    float* __restrict__ zTT, float* __restrict__ zSS, float* __restrict__ zTS) {

    __shared__ __bf16 As[2][8 * 128 * 8];
    __shared__ __bf16 Bs[2][8 * 128 * 8];

    int mode = blockIdx.z;
    const __bf16* A = (mode == 1) ? S : T;
    const __bf16* B = (mode == 0) ? T : S;
    const float* nA = (mode == 1) ? ns : nt;
    const float* nB = (mode == 0) ? nt : ns;
    float* z0 = (mode == 0) ? zTT : ((mode == 1) ? zSS : zTS);
    float* z1 = zTS + NN;

    int tid = threadIdx.x;
    int i0 = blockIdx.y * BM;
    int j0 = blockIdx.x * BN;

    int lane = tid & 63, wid = tid >> 6;
    int wr = wid >> 1, wc = wid & 1;
    int l15 = lane & 15, l4 = lane >> 4;

    // staging: thread t handles slots s = tid + 256*l (l=0..3); row = s&127, q = s>>7
    // all 4 slots share row sr; k-offsets q0*8 + 16*l
    int sr = tid & 127;
    int q0 = tid >> 7;
    const __bf16* gA = A + (size_t)(i0 + sr) * DD + q0 * 8;
    const __bf16* gB = B + (size_t)(j0 + sr) * DD + q0 * 8;

    f32x4 acc[4][4] = {};

    // prologue: stage tile 0 into buf 0
#pragma unroll
    for (int l = 0; l < 4; ++l) {
        load_lds16(gA + 16 * l, &As[0][(size_t)(tid + 256 * l) * 8]);
        load_lds16(gB + 16 * l, &Bs[0][(size_t)(tid + 256 * l) * 8]);
    }
    __syncthreads();

#pragma unroll
    for (int t = 0; t < NT; ++t) {
        int b = t & 1;
        if (t < NT - 1) {
            int k0 = (t + 1) * BK;
#pragma unroll
            for (int l = 0; l < 4; ++l) {
                load_lds16(gA + k0 + 16 * l, &As[b ^ 1][(size_t)(tid + 256 * l) * 8]);
                load_lds16(gB + k0 + 16 * l, &Bs[b ^ 1][(size_t)(tid + 256 * l) * 8]);
            }
        }
        bf16x8 af[2][4], bf[2][4];
#pragma unroll
        for (int kk = 0; kk < 2; ++kk) {
#pragma unroll
            for (int im = 0; im < 4; ++im)
                af[kk][im] = *(const bf16x8*)&As[b][((size_t)(kk * 4 + l4) * 128 + wr * 64 + im * 16 + l15) * 8];
#pragma unroll
            for (int in = 0; in < 4; ++in)
                bf[kk][in] = *(const bf16x8*)&Bs[b][((size_t)(kk * 4 + l4) * 128 + wc * 64 + in * 16 + l15) * 8];
        }
#pragma unroll
        for (int kk = 0; kk < 2; ++kk)
#pragma unroll
            for (int im = 0; im < 4; ++im)
#pragma unroll
                for (int in = 0; in < 4; ++in)
                    acc[im][in] = __builtin_amdgcn_mfma_f32_16x16x32_bf16(af[kk][im], bf[kk][in], acc[im][in], 0, 0, 0);
        __syncthreads();   // drains vmcnt (next tile staged) + protects buffer reuse
    }

    // epilogue: D = nA + nB - 2*dot -> exp -> predicate -> per-row sums
    float inv_scale = invscale_p[0];
    int ibase = i0 + wr * 64;
    int jbase = j0 + wc * 64;
    float nBv[4];
    int labBv[4], grpBv[4];
#pragma unroll
    for (int in = 0; in < 4; ++in) {
        int j = jbase + in * 16 + l15;
        nBv[in] = nB[j];
        labBv[in] = labels[j];
        grpBv[in] = groups[j];
    }
#pragma unroll
    for (int im = 0; im < 4; ++im) {
#pragma unroll
        for (int j = 0; j < 4; ++j) {
            int row = ibase + im * 16 + l4 * 4 + j;
            float ni = nA[row];
            int li = labels[row];
            int gi = groups[row];
            float s0 = 0.0f, s1 = 0.0f;
#pragma unroll
            for (int in = 0; in < 4; ++in) {
                float d = ni + nBv[in] - 2.0f * acc[im][in][j];
                d = fmaxf(d, 1e-12f);
                float kv = __expf(-d * inv_scale);
                bool ok = (li == labBv[in]);
                if (mode == 1) ok = ok && (gi == grpBv[in]);
                if (mode == 2) {
                    s0 += (ok && grpBv[in] == 0) ? kv : 0.0f;
                    s1 += (ok && grpBv[in] == 1) ? kv : 0.0f;
                } else {
                    s0 += ok ? kv : 0.0f;
                }
            }
#pragma unroll
            for (int o = 1; o < 16; o <<= 1) {
                s0 += __shfl_xor(s0, o);
                if (mode == 2) s1 += __shfl_xor(s1, o);
            }
            if (l15 == 0) {
                atomicAdd(&z0[row], s0);
                if (mode == 2) atomicAdd(&z1[row], s1);
            }
        }
    }
}

// ---------------------------------------------------------------------------
// Kernel 5: bucket per-row sums, final scalar.
// ---------------------------------------------------------------------------
__global__ void k_final(const int* __restrict__ labels, const int* __restrict__ groups,
                        const float* __restrict__ zTT, const float* __restrict__ zSS,
                        const float* __restrict__ zTS, float* __restrict__ out) {
    __shared__ float cnt_t[NC], cnt_s[NC * NG];
    __shared__ float nTT[NC], nSS[NC * NG], nTS[NC * NG];
    int tid = threadIdx.x;
    if (tid < NC) { cnt_t[tid] = 0.0f; nTT[tid] = 0.0f; }
    if (tid < NC * NG) { cnt_s[tid] = 0.0f; nSS[tid] = 0.0f; nTS[tid] = 0.0f; }
    __syncthreads();
    for (int i = tid; i < NN; i += 256) {
        int l = labels[i], g = groups[i];
        atomicAdd(&cnt_t[l], 1.0f);
        atomicAdd(&cnt_s[l * NG + g], 1.0f);
        atomicAdd(&nTT[l], zTT[i]);
        atomicAdd(&nSS[l * NG + g], zSS[i]);
        atomicAdd(&nTS[l * NG + 0], zTS[i]);
        atomicAdd(&nTS[l * NG + 1], zTS[NN + i]);
    }
    __syncthreads();
    if (tid == 0) {
        float total = 0.0f;
        for (int c = 0; c < NC; ++c) {
            float ntc = cnt_t[c];
            float sn = fmaxf(ntc, 1.0f);
            float meanTT = nTT[c] / (sn * sn);
            for (int g = 0; g < NG; ++g) {
                float nsg = cnt_s[c * NG + g];
                float ss = fmaxf(nsg, 1.0f);
                float meanSS = nSS[c * NG + g] / (ss * ss);
                float meanTS = nTS[c * NG + g] / (sn * ss);
                if (ntc > 0.0f && nsg > 0.0f)
                    total += meanTT + meanSS - 2.0f * meanTS;
            }
        }
        out[0] = 0.5f * total;
    }
}

// ---------------------------------------------------------------------------
// workspace layout:
// bytes [0, 4MB)      : teacher bf16 [4096][512]
// bytes [4MB, 8MB)    : student bf16 [4096][512]
// floats from 8MB:
//   +0      nt[4096]
//   +4096   ns[4096]
//   +8192   sumT[512]      <- zero region start
//   +8704   sumS[512]
//   +9216   zTT[4096]
//   +13312  zSS[4096]
//   +17408  zTS[2*4096]
//   +25600  invscale[1]    <- zero region end
// ---------------------------------------------------------------------------
extern "C" void kernel_launch(void* const* d_in, const int* in_sizes, int n_in,
                              void* d_out, int out_size, void* d_ws, size_t ws_size,
                              hipStream_t stream) {
    const float* fs     = (const float*)d_in[0];
    const float* ft     = (const float*)d_in[1];
    const int*   groups = (const int*)d_in[2];
    const int*   labels = (const int*)d_in[3];

    __bf16* Abf = (__bf16*)d_ws;                       // teacher
    __bf16* Bbf = (__bf16*)d_ws + (size_t)NN * DD;     // student
    float* wsf  = (float*)((char*)d_ws + (size_t)2 * NN * DD * sizeof(__bf16));
    float* nt   = wsf;
    float* ns   = wsf + 4096;
    float* sumT = wsf + 8192;
    float* sumS = wsf + 8704;
    float* zTT  = wsf + 9216;
    float* zSS  = wsf + 13312;
    float* zTS  = wsf + 17408;
    float* invs = wsf + 25600;

    hipMemsetAsync(wsf + 8192, 0, (size_t)17408 * sizeof(float), stream);

    k_prep<<<2048, 256, 0, stream>>>(ft, fs, Abf, Bbf, nt, ns);
    k_colsums<<<256, 256, 0, stream>>>(ft, fs, sumT, sumS);
    k_scale<<<1, 256, 0, stream>>>(nt, ns, sumT, sumS, invs);

    dim3 grid(NN / BN, NN / BM, 3);
    k_gram_all<<<grid, 256, 0, stream>>>(Abf, Bbf, nt, ns, labels, groups,
                                         invs, zTT, zSS, zTS);

    k_final<<<1, 256, 0, stream>>>(labels, groups, zTT, zSS, zTS, (float*)d_out);
}

// Round 4
// 195.361 us; speedup vs baseline: 3.5779x; 1.2690x over previous
//
#include <hip/hip_runtime.h>
#include <math.h>

#define NN 4096
#define DD 512
#define NC 10
#define NG 2

#define BM 256
#define BN 128
#define BK 32
#define NT (DD / BK)   // 16 K-steps

typedef __bf16 bf16x8 __attribute__((ext_vector_type(8)));
typedef __bf16 bf16x4 __attribute__((ext_vector_type(4)));
typedef float f32x4 __attribute__((ext_vector_type(4)));

__device__ __forceinline__ void load_lds16(const __bf16* g, __bf16* l) {
    __builtin_amdgcn_global_load_lds((const __attribute__((address_space(1))) void*)g,
                                     (__attribute__((address_space(3))) void*)l, 16, 0, 0);
}

// ---------------------------------------------------------------------------
// Kernel 1: fused fp32->bf16 convert + per-row squared norms (fp32 exact).
// ---------------------------------------------------------------------------
__global__ void k_prep(const float* __restrict__ ft, const float* __restrict__ fs,
                       __bf16* __restrict__ at, __bf16* __restrict__ as_,
                       float* __restrict__ nt, float* __restrict__ ns) {
    int wid  = threadIdx.x >> 6;
    int lane = threadIdx.x & 63;
    int r = blockIdx.x * 4 + wid;
    const float* src; __bf16* bdst; float* ndst; int row;
    if (r < NN) { src = ft; bdst = at;  ndst = nt; row = r; }
    else        { src = fs; bdst = as_; ndst = ns; row = r - NN; }
    const float4* p = (const float4*)(src + (size_t)row * DD);
    float s = 0.0f;
#pragma unroll
    for (int c = 0; c < 2; ++c) {
        float4 v = p[lane + 64 * c];
        s += v.x * v.x + v.y * v.y + v.z * v.z + v.w * v.w;
        bf16x4 b;
        b[0] = (__bf16)v.x; b[1] = (__bf16)v.y; b[2] = (__bf16)v.z; b[3] = (__bf16)v.w;
        *(bf16x4*)(bdst + (size_t)row * DD + (lane + 64 * c) * 4) = b;
    }
#pragma unroll
    for (int o = 32; o; o >>= 1) s += __shfl_xor(s, o);
    if (lane == 0) ndst[row] = s;
}

// ---------------------------------------------------------------------------
// Kernel 2: column sums (fp32 inputs, for closed-form sigma).
// ---------------------------------------------------------------------------
__global__ void k_colsums(const float* __restrict__ ft, const float* __restrict__ fs,
                          float* __restrict__ sumT, float* __restrict__ sumS) {
    int b = blockIdx.x;
    int mat = b & 1;
    int chunk = b >> 1;
    const float* src = mat ? fs : ft;
    float* dst = mat ? sumS : sumT;
    int r0 = chunk * 32;
    int c0 = threadIdx.x, c1 = threadIdx.x + 256;
    float a0 = 0.0f, a1 = 0.0f;
    for (int r = r0; r < r0 + 32; ++r) {
        a0 += src[(size_t)r * DD + c0];
        a1 += src[(size_t)r * DD + c1];
    }
    atomicAdd(&dst[c0], a0);
    atomicAdd(&dst[c1], a1);
}

// ---------------------------------------------------------------------------
// Kernel 3: inv_scale = 1/(2*sigma_avg), sigma closed form.
// ---------------------------------------------------------------------------
__global__ void k_scale(const float* __restrict__ nt, const float* __restrict__ ns,
                        const float* __restrict__ sumT, const float* __restrict__ sumS,
                        float* __restrict__ invscale) {
    __shared__ float red[8];
    int tid = threadIdx.x;
    float s = 0.0f;
    for (int i = tid; i < NN; i += 256) s += nt[i] + ns[i];
    float d = 0.0f;
    for (int i = tid; i < DD; i += 256) d += sumT[i] * sumS[i];
#pragma unroll
    for (int o = 32; o; o >>= 1) { s += __shfl_xor(s, o); d += __shfl_xor(d, o); }
    int wid = tid >> 6, lane = tid & 63;
    if (lane == 0) { red[wid] = s; red[wid + 4] = d; }
    __syncthreads();
    if (tid == 0) {
        float S  = red[0] + red[1] + red[2] + red[3];
        float Dt = red[4] + red[5] + red[6] + red[7];
        float sigma = S / (float)NN - 2.0f * Dt / ((float)NN * (float)NN);
        invscale[0] = 1.0f / (2.0f * sigma);
    }
}

// ---------------------------------------------------------------------------
// Kernel 4: all three Grams in one launch (blockIdx.z = mode).
// mode 0 = TT (label match), 1 = SS (label&&group), 2 = TS (split by grpB).
// 256x128 tile, 8 waves (4Mx2N), wave tile 64x64 via 4x4 mfma_f32_16x16x32_bf16,
// BK=32, double-buffered LDS with stage-ahead. 48 KB LDS; VGPR capped via
// __launch_bounds__(512,4) -> 2 blocks/CU (16 waves) for latency overlap.
// LDS per buffer: A [4][256][8], B [4][128][8] bf16; conflict-free ds_read_b128.
// ---------------------------------------------------------------------------
__global__ __launch_bounds__(512, 4) void k_gram_all(
    const __bf16* __restrict__ T, const __bf16* __restrict__ S,
    const float* __restrict__ nt, const float* __restrict__ ns,
    const int* __restrict__ labels, const int* __restrict__ groups,
    const float* __restrict__ invscale_p,
    float* __restrict__ zTT, float* __restrict__ zSS, float* __restrict__ zTS) {

    __shared__ __bf16 As[2][4 * 256 * 8];
    __shared__ __bf16 Bs[2][4 * 128 * 8];

    int mode = blockIdx.z;
    const __bf16* A = (mode == 1) ? S : T;
    const __bf16* B = (mode == 0) ? T : S;
    const float* nA = (mode == 1) ? ns : nt;
    const float* nB = (mode == 0) ? nt : ns;
    float* z0 = (mode == 0) ? zTT : ((mode == 1) ? zSS : zTS);
    float* z1 = zTS + NN;

    int tid = threadIdx.x;
    int i0 = blockIdx.y * BM;
    int j0 = blockIdx.x * BN;

    int lane = tid & 63, wid = tid >> 6;
    int wr = wid >> 1, wc = wid & 1;          // 4 x 2 wave grid
    int l15 = lane & 15, l4 = lane >> 4;

    // staging:
    // A slots s = tid, tid+512 : row = tid&255 (same for both), q = tid>>8 and +2
    // B slot  s = tid          : row = tid&127, q = tid>>7
    int ra = tid & 255;
    int qa = tid >> 8;                        // 0..1
    int rb = tid & 127;
    int qb = tid >> 7;                        // 0..3
    const __bf16* gA = A + (size_t)(i0 + ra) * DD + qa * 8;   // +16 for 2nd slot
    const __bf16* gB = B + (size_t)(j0 + rb) * DD + qb * 8;

    f32x4 acc[4][4] = {};

    // prologue: stage tile 0 into buf 0
    load_lds16(gA,      &As[0][(size_t)tid * 8]);
    load_lds16(gA + 16, &As[0][(size_t)(tid + 512) * 8]);
    load_lds16(gB,      &Bs[0][(size_t)tid * 8]);
    __syncthreads();

#pragma unroll 2
    for (int t = 0; t < NT; ++t) {
        int b = t & 1;
        if (t < NT - 1) {
            int k0 = (t + 1) * BK;
            load_lds16(gA + k0,      &As[b ^ 1][(size_t)tid * 8]);
            load_lds16(gA + k0 + 16, &As[b ^ 1][(size_t)(tid + 512) * 8]);
            load_lds16(gB + k0,      &Bs[b ^ 1][(size_t)tid * 8]);
        }
        bf16x8 af[4], bf[4];
#pragma unroll
        for (int im = 0; im < 4; ++im)
            af[im] = *(const bf16x8*)&As[b][((size_t)l4 * 256 + wr * 64 + im * 16 + l15) * 8];
#pragma unroll
        for (int in = 0; in < 4; ++in)
            bf[in] = *(const bf16x8*)&Bs[b][((size_t)l4 * 128 + wc * 64 + in * 16 + l15) * 8];
#pragma unroll
        for (int im = 0; im < 4; ++im)
#pragma unroll
            for (int in = 0; in < 4; ++in)
                acc[im][in] = __builtin_amdgcn_mfma_f32_16x16x32_bf16(af[im], bf[in], acc[im][in], 0, 0, 0);
        __syncthreads();   // next tile staged + buffer reuse protected
    }

    // epilogue: D = nA + nB - 2*dot -> exp -> predicate -> per-row sums
    float inv_scale = invscale_p[0];
    int ibase = i0 + wr * 64;
    int jbase = j0 + wc * 64;
    float nBv[4];
    int labBv[4], grpBv[4];
#pragma unroll
    for (int in = 0; in < 4; ++in) {
        int j = jbase + in * 16 + l15;
        nBv[in] = nB[j];
        labBv[in] = labels[j];
        grpBv[in] = groups[j];
    }
#pragma unroll
    for (int im = 0; im < 4; ++im) {
#pragma unroll
        for (int j = 0; j < 4; ++j) {
            int row = ibase + im * 16 + l4 * 4 + j;
            float ni = nA[row];
            int li = labels[row];
            int gi = groups[row];
            float s0 = 0.0f, s1 = 0.0f;
#pragma unroll
            for (int in = 0; in < 4; ++in) {
                float d = ni + nBv[in] - 2.0f * acc[im][in][j];
                d = fmaxf(d, 1e-12f);
                float kv = __expf(-d * inv_scale);
                bool ok = (li == labBv[in]);
                if (mode == 1) ok = ok && (gi == grpBv[in]);
                if (mode == 2) {
                    s0 += (ok && grpBv[in] == 0) ? kv : 0.0f;
                    s1 += (ok && grpBv[in] == 1) ? kv : 0.0f;
                } else {
                    s0 += ok ? kv : 0.0f;
                }
            }
#pragma unroll
            for (int o = 1; o < 16; o <<= 1) {
                s0 += __shfl_xor(s0, o);
                if (mode == 2) s1 += __shfl_xor(s1, o);
            }
            if (l15 == 0) {
                atomicAdd(&z0[row], s0);
                if (mode == 2) atomicAdd(&z1[row], s1);
            }
        }
    }
}

// ---------------------------------------------------------------------------
// Kernel 5: bucket per-row sums, final scalar.
// ---------------------------------------------------------------------------
__global__ void k_final(const int* __restrict__ labels, const int* __restrict__ groups,
                        const float* __restrict__ zTT, const float* __restrict__ zSS,
                        const float* __restrict__ zTS, float* __restrict__ out) {
    __shared__ float cnt_t[NC], cnt_s[NC * NG];
    __shared__ float nTT[NC], nSS[NC * NG], nTS[NC * NG];
    int tid = threadIdx.x;
    if (tid < NC) { cnt_t[tid] = 0.0f; nTT[tid] = 0.0f; }
    if (tid < NC * NG) { cnt_s[tid] = 0.0f; nSS[tid] = 0.0f; nTS[tid] = 0.0f; }
    __syncthreads();
    for (int i = tid; i < NN; i += 256) {
        int l = labels[i], g = groups[i];
        atomicAdd(&cnt_t[l], 1.0f);
        atomicAdd(&cnt_s[l * NG + g], 1.0f);
        atomicAdd(&nTT[l], zTT[i]);
        atomicAdd(&nSS[l * NG + g], zSS[i]);
        atomicAdd(&nTS[l * NG + 0], zTS[i]);
        atomicAdd(&nTS[l * NG + 1], zTS[NN + i]);
    }
    __syncthreads();
    if (tid == 0) {
        float total = 0.0f;
        for (int c = 0; c < NC; ++c) {
            float ntc = cnt_t[c];
            float sn = fmaxf(ntc, 1.0f);
            float meanTT = nTT[c] / (sn * sn);
            for (int g = 0; g < NG; ++g) {
                float nsg = cnt_s[c * NG + g];
                float ss = fmaxf(nsg, 1.0f);
                float meanSS = nSS[c * NG + g] / (ss * ss);
                float meanTS = nTS[c * NG + g] / (sn * ss);
                if (ntc > 0.0f && nsg > 0.0f)
                    total += meanTT + meanSS - 2.0f * meanTS;
            }
        }
        out[0] = 0.5f * total;
    }
}

// ---------------------------------------------------------------------------
// workspace layout:
// bytes [0, 4MB)      : teacher bf16 [4096][512]
// bytes [4MB, 8MB)    : student bf16 [4096][512]
// floats from 8MB:
//   +0      nt[4096]
//   +4096   ns[4096]
//   +8192   sumT[512]      <- zero region start
//   +8704   sumS[512]
//   +9216   zTT[4096]
//   +13312  zSS[4096]
//   +17408  zTS[2*4096]
//   +25600  invscale[1]    <- zero region end
// ---------------------------------------------------------------------------
extern "C" void kernel_launch(void* const* d_in, const int* in_sizes, int n_in,
                              void* d_out, int out_size, void* d_ws, size_t ws_size,
                              hipStream_t stream) {
    const float* fs     = (const float*)d_in[0];
    const float* ft     = (const float*)d_in[1];
    const int*   groups = (const int*)d_in[2];
    const int*   labels = (const int*)d_in[3];

    __bf16* Abf = (__bf16*)d_ws;                       // teacher
    __bf16* Bbf = (__bf16*)d_ws + (size_t)NN * DD;     // student
    float* wsf  = (float*)((char*)d_ws + (size_t)2 * NN * DD * sizeof(__bf16));
    float* nt   = wsf;
    float* ns   = wsf + 4096;
    float* sumT = wsf + 8192;
    float* sumS = wsf + 8704;
    float* zTT  = wsf + 9216;
    float* zSS  = wsf + 13312;
    float* zTS  = wsf + 17408;
    float* invs = wsf + 25600;

    hipMemsetAsync(wsf + 8192, 0, (size_t)17408 * sizeof(float), stream);

    k_prep<<<2048, 256, 0, stream>>>(ft, fs, Abf, Bbf, nt, ns);
    k_colsums<<<256, 256, 0, stream>>>(ft, fs, sumT, sumS);
    k_scale<<<1, 256, 0, stream>>>(nt, ns, sumT, sumS, invs);

    dim3 grid(NN / BN, NN / BM, 3);
    k_gram_all<<<grid, 512, 0, stream>>>(Abf, Bbf, nt, ns, labels, groups,
                                         invs, zTT, zSS, zTS);

    k_final<<<1, 256, 0, stream>>>(labels, groups, zTT, zSS, zTS, (float*)d_out);
}